// Round 17
// baseline (149.600 us; speedup 1.0000x reference)
//
#include <hip/hip_runtime.h>
#include <cstdint>

#define T_  2048
#define D_  64
#define BH_ 32
#define W_  256
#define GP  72   // Gs row pitch in shorts (144 B)

typedef float f32x4 __attribute__((ext_vector_type(4)));
using bf16x8 = __attribute__((ext_vector_type(8))) short;   // 8 bf16 in 4 VGPRs

__device__ inline unsigned short f2bf(float x) {            // RNE fp32->bf16
  unsigned u = __float_as_uint(x);
  u = (u + 0x7fffu + ((u >> 16) & 1u)) >> 16;
  return (unsigned short)u;
}

__device__ inline bf16x8 cvt8(const f32x4 lo, const f32x4 hi) {
  bf16x8 r;
  r[0] = (short)f2bf(lo.x); r[1] = (short)f2bf(lo.y);
  r[2] = (short)f2bf(lo.z); r[3] = (short)f2bf(lo.w);
  r[4] = (short)f2bf(hi.x); r[5] = (short)f2bf(hi.y);
  r[6] = (short)f2bf(hi.z); r[7] = (short)f2bf(hi.w);
  return r;
}

// Band-only kernel. d_out is pre-zeroed by hipMemsetAsync (the runtime fill
// path sustains ~6.7 TB/s — every in-kernel zero variant measured 3.6-4.8).
// One block (256 thr = 4 waves) per (bh, 128-row strip); wave wv owns rows
// ib0..ib0+31: scan -> gene fitness -> bf16 LDS (wave-private rows), then
// banded MFMA writing ONLY quads intersecting the true window [i-255, i]
// (interior masked zeros are already zero from the memset). Regular f32x4
// stores: L2 merges the 64B row segments across jt iterations (r14 best).
__global__ __launch_bounds__(256, 2) void k_band(const float* __restrict__ pop,
                                                 float* __restrict__ out) {
  __shared__ unsigned short Gs[128 * GP];
  const int unit = blockIdx.x;            // 0..511
  const int i0   = (unit & 15) * 128;
  const int bh   = unit >> 4;
  const int tid  = threadIdx.x;
  const int lane = tid & 63, wv = tid >> 6;   // wv: 0..3
  const int l15 = lane & 15, l4 = lane >> 4;
  const float* Pb = pop + (size_t)bh * T_ * D_;
  float*       Ob = out + (size_t)bh * T_ * T_;
  const int ib0 = i0 + wv * 32;

  // ---- scan (chunked, register-lean): rows ib0..ib0+31 -> Gs (bf16) ----
  {
    const int d = lane;                   // lane == feature dim
    const float* P = Pb + d;

    int s0 = ib0 - (W_ - 1); if (s0 < 0) s0 = 0;
    const int jend = ib0 + 1;
    float p0=0.f,p1=0.f,p2=0.f,p3=0.f,p4=0.f,p5=0.f,p6=0.f,p7=0.f;
    int j = s0;
    for (; j + 8 <= jend; j += 8) {
      p0 += P[(size_t)(j+0)*D_]; p1 += P[(size_t)(j+1)*D_];
      p2 += P[(size_t)(j+2)*D_]; p3 += P[(size_t)(j+3)*D_];
      p4 += P[(size_t)(j+4)*D_]; p5 += P[(size_t)(j+5)*D_];
      p6 += P[(size_t)(j+6)*D_]; p7 += P[(size_t)(j+7)*D_];
    }
    for (; j < jend; ++j) p0 += P[(size_t)j*D_];
    float run = ((p0+p1)+(p2+p3)) + ((p4+p5)+(p6+p7));   // window sum @ row ib0

    #pragma unroll
    for (int c = 0; c < 4; ++c) {         // 4 chunks x 8 rows
      float av[8], dv[8];
      #pragma unroll
      for (int k = 0; k < 8; ++k) {
        const int r = c * 8 + k;
        av[k] = (r == 0) ? 0.f : P[(size_t)(ib0 + r) * D_];
        const int jd = ib0 + r - W_;
        dv[k] = (r == 0 || jd < 0) ? 0.f : P[(size_t)jd * D_];
      }
      float rinv[8], sv[8];
      #pragma unroll
      for (int k = 0; k < 8; ++k) {
        run += av[k] - dv[k];
        const int i = ib0 + c * 8 + k;
        const float cnt = (i + 1 < W_) ? (float)(i + 1) : (float)W_;
        rinv[k] = 1.0f / (run / cnt + 0.5f);
        sv[k] = rinv[k];
      }
      #pragma unroll
      for (int m = 32; m >= 1; m >>= 1) {
        #pragma unroll
        for (int k = 0; k < 8; ++k) sv[k] += __shfl_xor(sv[k], m);
      }
      #pragma unroll
      for (int k = 0; k < 8; ++k) {
        const int i = ib0 + c * 8 + k;
        const float cnt = (i + 1 < W_) ? (float)(i + 1) : (float)W_;
        float rowsum = cnt * (64.0f / sv[k] - 0.5f);
        rowsum = fmaxf(rowsum, 1e-10f);
        Gs[(wv * 32 + c * 8 + k) * GP + d] = f2bf(rinv[k] / (rowsum * sv[k]));
      }
    }
  }
  // intra-wave LDS write->read ordering handled by compiler lgkmcnt waits

  // ---- band MFMA: gfs fragments from this wave's own Gs rows ----
  const bf16x8 g00 = *reinterpret_cast<const bf16x8*>(&Gs[(wv*32      + l15) * GP      + l4*8]);
  const bf16x8 g01 = *reinterpret_cast<const bf16x8*>(&Gs[(wv*32      + l15) * GP + 32 + l4*8]);
  const bf16x8 g10 = *reinterpret_cast<const bf16x8*>(&Gs[(wv*32 + 16 + l15) * GP      + l4*8]);
  const bf16x8 g11 = *reinterpret_cast<const bf16x8*>(&Gs[(wv*32 + 16 + l15) * GP + 32 + l4*8]);

  // live tiles for this wave's rows: jb in [ib0-256, ib0+16] (18 tiles)
  for (int t = 0; t < 18; ++t) {
    const int jb = ib0 - 256 + t * 16;
    if (jb < 0) continue;                 // uniform across the wave
    const float* prow = &Pb[(size_t)(jb + l15) * D_];
    const f32x4 q0 = *reinterpret_cast<const f32x4*>(prow + l4*8);
    const f32x4 q1 = *reinterpret_cast<const f32x4*>(prow + l4*8 + 4);
    const f32x4 q2 = *reinterpret_cast<const f32x4*>(prow + 32 + l4*8);
    const f32x4 q3 = *reinterpret_cast<const f32x4*>(prow + 32 + l4*8 + 4);
    const bf16x8 p0 = cvt8(q0, q1);       // k = l4*8 .. +7
    const bf16x8 p1 = cvt8(q2, q3);       // k = 32 + l4*8 .. +7

    f32x4 c0 = {0.f, 0.f, 0.f, 0.f};
    f32x4 c1 = {0.f, 0.f, 0.f, 0.f};
    c0 = __builtin_amdgcn_mfma_f32_16x16x32_bf16(p0, g00, c0, 0, 0, 0);
    c0 = __builtin_amdgcn_mfma_f32_16x16x32_bf16(p1, g01, c0, 0, 0, 0);
    c1 = __builtin_amdgcn_mfma_f32_16x16x32_bf16(p0, g10, c1, 0, 0, 0);
    c1 = __builtin_amdgcn_mfma_f32_16x16x32_bf16(p1, g11, c1, 0, 0, 0);

    const int jq = jb + l4 * 4;           // 4 consecutive out-cols per lane
    {
      const int i = ib0 + l15;
      if (jq <= i && jq + 3 >= i - 255) { // quad intersects live window
        f32x4 v;
        #pragma unroll
        for (int r = 0; r < 4; ++r)
          v[r] = ((unsigned)(i - (jq + r)) < 256u) ? c0[r] : 0.f;
        *reinterpret_cast<f32x4*>(&Ob[(size_t)i * T_ + jq]) = v;
      }
    }
    {
      const int i = ib0 + 16 + l15;
      if (jq <= i && jq + 3 >= i - 255) {
        f32x4 v;
        #pragma unroll
        for (int r = 0; r < 4; ++r)
          v[r] = ((unsigned)(i - (jq + r)) < 256u) ? c1[r] : 0.f;
        *reinterpret_cast<f32x4*>(&Ob[(size_t)i * T_ + jq]) = v;
      }
    }
  }
}

extern "C" void kernel_launch(void* const* d_in, const int* in_sizes, int n_in,
                              void* d_out, int out_size, void* d_ws, size_t ws_size,
                              hipStream_t stream) {
  const float* pop = (const float*)d_in[0];
  float* out = (float*)d_out;
  // Zero the whole output via the runtime fill path (~6.7 TB/s, graph-capturable
  // memset node), then write only the true causal-window band.
  hipMemsetAsync(out, 0, (size_t)out_size * sizeof(float), stream);
  hipLaunchKernelGGL(k_band, dim3(16 * BH_), dim3(256), 0, stream, pop, out);
}

// Round 18
// 114.387 us; speedup vs baseline: 1.3078x; 1.3078x over previous
//
#include <hip/hip_runtime.h>
#include <cstdint>

#define T_  2048
#define D_  64
#define BH_ 32
#define W_  256
#define GP  72   // LDS row pitch in shorts (144 B)

typedef float f32x4 __attribute__((ext_vector_type(4)));
using bf16x8 = __attribute__((ext_vector_type(8))) short;   // 8 bf16 in 4 VGPRs

__device__ inline unsigned short f2bf(float x) {            // RNE fp32->bf16
  unsigned u = __float_as_uint(x);
  u = (u + 0x7fffu + ((u >> 16) & 1u)) >> 16;
  return (unsigned short)u;
}

__device__ inline bf16x8 cvt8(const f32x4 lo, const f32x4 hi) {
  bf16x8 r;
  r[0] = (short)f2bf(lo.x); r[1] = (short)f2bf(lo.y);
  r[2] = (short)f2bf(lo.z); r[3] = (short)f2bf(lo.w);
  r[4] = (short)f2bf(hi.x); r[5] = (short)f2bf(hi.y);
  r[6] = (short)f2bf(hi.z); r[7] = (short)f2bf(hi.w);
  return r;
}

// BEST CONFIG (r14, 114.7 us): one block (512 thr) per (bh, 128-row strip),
// wave-specialized:
//  waves 0-3 (band): scan -> gene fitness -> bf16 LDS (wave-private rows) ->
//    banded MFMA (swapped operands: lane = out-row, regs = 4 consecutive
//    out-cols) -> REGULAR f32x4 stores (L2 merges 64B segments; NT here hurts).
//  waves 4-7 (zero): NT zero streaming of out-of-band segments, rows
//    interleaved mod 4 (leapfrog sweep). NT is essential: regular bulk zeros
//    thrash L2 against pop reads (r15: 115 -> 152 us).
// Separate waves = separate vmcnt: store backlog never gates band loads (r11).
// Tested-and-rejected: role-parity fusion (231), serial two-kernel (177),
// zero-first phase order (156), LDS-staged NT burst (127), memset+band (150).
__global__ __launch_bounds__(512, 4) void fused_strip(const float* __restrict__ pop,
                                                      float* __restrict__ out) {
  __shared__ unsigned short Gs[128 * GP];
  const int unit = blockIdx.x;            // 0..511
  const int i0   = (unit & 15) * 128;
  const int bh   = unit >> 4;
  const int tid  = threadIdx.x;
  const int lane = tid & 63, wv = tid >> 6;   // wv: 0..7
  const float* Pb = pop + (size_t)bh * T_ * D_;
  float*       Ob = out + (size_t)bh * T_ * T_;

  if (wv >= 4) {
    // -------- zero role: rows r == (wv-4) mod 4, NT leapfrog sweep ----------
    const int q = wv - 4;
    int Lz = i0 - 256; if (Lz < 0) Lz = 0;
    const int L4n = Lz >> 2;
    const int R   = i0 + 128;
    const int W4r = (T_ - R) >> 2;
    const f32x4 z4 = {0.f, 0.f, 0.f, 0.f};
    for (int r = q; r < 128; r += 4) {
      float* orow = Ob + (size_t)(i0 + r) * T_;
      f32x4* oL = reinterpret_cast<f32x4*>(orow);
      for (int c = lane; c < L4n; c += 64)
        __builtin_nontemporal_store(z4, &oL[c]);
      f32x4* oR = reinterpret_cast<f32x4*>(orow + R);
      for (int c = lane; c < W4r; c += 64)
        __builtin_nontemporal_store(z4, &oR[c]);
    }
    return;
  }

  // -------- band role: wave wv owns rows ib0..ib0+31 --------
  const int l15 = lane & 15, l4 = lane >> 4;
  const int ib0 = i0 + wv * 32;

  // ---- scan (chunked, register-lean): rows ib0..ib0+31 -> Gs (bf16) ----
  {
    const int d = lane;                   // lane == feature dim
    const float* P = Pb + d;

    int s0 = ib0 - (W_ - 1); if (s0 < 0) s0 = 0;
    const int jend = ib0 + 1;
    float p0=0.f,p1=0.f,p2=0.f,p3=0.f,p4=0.f,p5=0.f,p6=0.f,p7=0.f;
    int j = s0;
    for (; j + 8 <= jend; j += 8) {
      p0 += P[(size_t)(j+0)*D_]; p1 += P[(size_t)(j+1)*D_];
      p2 += P[(size_t)(j+2)*D_]; p3 += P[(size_t)(j+3)*D_];
      p4 += P[(size_t)(j+4)*D_]; p5 += P[(size_t)(j+5)*D_];
      p6 += P[(size_t)(j+6)*D_]; p7 += P[(size_t)(j+7)*D_];
    }
    for (; j < jend; ++j) p0 += P[(size_t)j*D_];
    float run = ((p0+p1)+(p2+p3)) + ((p4+p5)+(p6+p7));   // window sum @ row ib0

    #pragma unroll
    for (int c = 0; c < 4; ++c) {         // 4 chunks x 8 rows
      float av[8], dv[8];
      #pragma unroll
      for (int k = 0; k < 8; ++k) {
        const int r = c * 8 + k;
        av[k] = (r == 0) ? 0.f : P[(size_t)(ib0 + r) * D_];
        const int jd = ib0 + r - W_;
        dv[k] = (r == 0 || jd < 0) ? 0.f : P[(size_t)jd * D_];
      }
      float rinv[8], sv[8];
      #pragma unroll
      for (int k = 0; k < 8; ++k) {
        run += av[k] - dv[k];
        const int i = ib0 + c * 8 + k;
        const float cnt = (i + 1 < W_) ? (float)(i + 1) : (float)W_;
        rinv[k] = 1.0f / (run / cnt + 0.5f);
        sv[k] = rinv[k];
      }
      #pragma unroll
      for (int m = 32; m >= 1; m >>= 1) {
        #pragma unroll
        for (int k = 0; k < 8; ++k) sv[k] += __shfl_xor(sv[k], m);
      }
      #pragma unroll
      for (int k = 0; k < 8; ++k) {
        const int i = ib0 + c * 8 + k;
        const float cnt = (i + 1 < W_) ? (float)(i + 1) : (float)W_;
        float rowsum = cnt * (64.0f / sv[k] - 0.5f);
        rowsum = fmaxf(rowsum, 1e-10f);
        Gs[(wv * 32 + c * 8 + k) * GP + d] = f2bf(rinv[k] / (rowsum * sv[k]));
      }
    }
  }
  // intra-wave LDS write->read ordering handled by compiler lgkmcnt waits

  // ---- band MFMA: gfs fragments from this wave's own Gs rows ----
  const bf16x8 g00 = *reinterpret_cast<const bf16x8*>(&Gs[(wv*32      + l15) * GP      + l4*8]);
  const bf16x8 g01 = *reinterpret_cast<const bf16x8*>(&Gs[(wv*32      + l15) * GP + 32 + l4*8]);
  const bf16x8 g10 = *reinterpret_cast<const bf16x8*>(&Gs[(wv*32 + 16 + l15) * GP      + l4*8]);
  const bf16x8 g11 = *reinterpret_cast<const bf16x8*>(&Gs[(wv*32 + 16 + l15) * GP + 32 + l4*8]);

  for (int jt = 0; jt < 24; ++jt) {
    const int jb = i0 - 256 + jt * 16;
    if (jb < 0) continue;                 // uniform across the wave
    const float* prow = &Pb[(size_t)(jb + l15) * D_];
    const f32x4 q0 = *reinterpret_cast<const f32x4*>(prow + l4*8);
    const f32x4 q1 = *reinterpret_cast<const f32x4*>(prow + l4*8 + 4);
    const f32x4 q2 = *reinterpret_cast<const f32x4*>(prow + 32 + l4*8);
    const f32x4 q3 = *reinterpret_cast<const f32x4*>(prow + 32 + l4*8 + 4);
    const bf16x8 p0 = cvt8(q0, q1);       // k = l4*8 .. +7
    const bf16x8 p1 = cvt8(q2, q3);       // k = 32 + l4*8 .. +7

    f32x4 c0 = {0.f, 0.f, 0.f, 0.f};
    f32x4 c1 = {0.f, 0.f, 0.f, 0.f};
    c0 = __builtin_amdgcn_mfma_f32_16x16x32_bf16(p0, g00, c0, 0, 0, 0);
    c0 = __builtin_amdgcn_mfma_f32_16x16x32_bf16(p1, g01, c0, 0, 0, 0);
    c1 = __builtin_amdgcn_mfma_f32_16x16x32_bf16(p0, g10, c1, 0, 0, 0);
    c1 = __builtin_amdgcn_mfma_f32_16x16x32_bf16(p1, g11, c1, 0, 0, 0);

    const int jq = jb + l4 * 4;           // 4 consecutive out-cols per lane
    {
      const int i = ib0 + l15;
      f32x4 v;
      #pragma unroll
      for (int r = 0; r < 4; ++r)
        v[r] = ((unsigned)(i - (jq + r)) < 256u) ? c0[r] : 0.f;
      *reinterpret_cast<f32x4*>(&Ob[(size_t)i * T_ + jq]) = v;   // regular: L2 merges
    }
    {
      const int i = ib0 + 16 + l15;
      f32x4 v;
      #pragma unroll
      for (int r = 0; r < 4; ++r)
        v[r] = ((unsigned)(i - (jq + r)) < 256u) ? c1[r] : 0.f;
      *reinterpret_cast<f32x4*>(&Ob[(size_t)i * T_ + jq]) = v;
    }
  }
}

extern "C" void kernel_launch(void* const* d_in, const int* in_sizes, int n_in,
                              void* d_out, int out_size, void* d_ws, size_t ws_size,
                              hipStream_t stream) {
  const float* pop = (const float*)d_in[0];
  float* out = (float*)d_out;
  dim3 blk(512);
  hipLaunchKernelGGL(fused_strip, dim3(16 * BH_), blk, 0, stream, pop, out);
}